// Round 1
// baseline (190.022 us; speedup 1.0000x reference)
//
#include <hip/hip_runtime.h>

#define NN 20000
#define EE 320000

typedef unsigned int  u32;
typedef unsigned short u16;

typedef _Float16 h8 __attribute__((ext_vector_type(8)));
typedef _Float16 h2 __attribute__((ext_vector_type(2)));
typedef float    f4 __attribute__((ext_vector_type(4)));

union U16 { uint4 u; h8 h; };

__device__ inline u32 phh(float a, float b){
  h2 v; v[0] = (_Float16)a; v[1] = (_Float16)b;
  return __builtin_bit_cast(u32, v);
}
__device__ inline u16 f2h_u(float a){
  _Float16 h = (_Float16)a;
  return __builtin_bit_cast(u16, h);
}
__device__ inline float2 up2(u32 u){
  h2 v = __builtin_bit_cast(h2, u);
  return make_float2((float)v[0], (float)v[1]);
}
__device__ inline h8 pack8(float4 a, float4 b){
  U16 t;
  t.u.x = phh(a.x, a.y);
  t.u.y = phh(a.z, a.w);
  t.u.z = phh(b.x, b.y);
  t.u.w = phh(b.z, b.w);
  return t.h;
}

// ---------------------------------------------------------------------------
// k0: pack all weights into MFMA B-fragment order, f16.
// B-frag layout for 16x16x32: lane holds B[k=(lane/16)*8+j][col=ct*16+lane%16]
// ws (u16 units):
//   [0,65536)        W2pack: [d][ct(8)][ks(4)][lane(64)][j(8)]  (cols 0-63=Wq, 64-127=Wk[d])
//   [65536,73728)    mw1pack: [ct(8)][ks(2)][lane][j]   (K=64)
//   [73728,90112)    mw2pack: [ct(8)][ks(4)][lane][j]
//   [90112,106496)   mt1pack
//   [106496,122880)  mt2pack
//   [122880, +5.12M) Q f16 [N][d*64+r]
//   [...,   +5.12M)  K f16 [N][d*64+r]
// ---------------------------------------------------------------------------
__global__ void k0_pack(const float* __restrict__ Wq, const float* __restrict__ Wk,
                        const float* __restrict__ w1w, const float* __restrict__ w2w,
                        const float* __restrict__ w1t, const float* __restrict__ w2t,
                        u16* __restrict__ pack)
{
  const int tot = 65536 + 8192 + 16384*3;
  for (int o = blockIdx.x*blockDim.x + threadIdx.x; o < tot; o += gridDim.x*blockDim.x){
    float v;
    if (o < 65536){
      int d = o >> 14, r = o & 16383;
      int ct = r >> 11, ks = (r >> 9) & 3, lane = (r >> 3) & 63, j = r & 7;
      int k = ks*32 + (lane >> 4)*8 + j, c = ct*16 + (lane & 15);
      v = (c < 64) ? Wq[k*64 + c] : Wk[((d << 7) + k)*64 + (c - 64)];
    } else if (o < 73728){
      int r = o - 65536;
      int ct = r >> 10, ks = (r >> 9) & 1, lane = (r >> 3) & 63, j = r & 7;
      int k = ks*32 + (lane >> 4)*8 + j, c = ct*16 + (lane & 15);
      v = w1w[k*128 + c];
    } else {
      int r = o - 73728;
      int m = r >> 14; r &= 16383;
      int ct = r >> 11, ks = (r >> 9) & 3, lane = (r >> 3) & 63, j = r & 7;
      int k = ks*32 + (lane >> 4)*8 + j, c = ct*16 + (lane & 15);
      const float* M = (m == 0) ? w2w : (m == 1) ? w1t : w2t;
      v = M[k*128 + c];
    }
    pack[o] = f2h_u(v);
  }
}

// ---------------------------------------------------------------------------
// k1: per-d projection GEMM: [N x 128] @ [128 x 128] -> q||k per node, f16.
// 4 waves/block, wave = 16 nodes. A-frags straight from global X (f32->f16),
// B-frags from packed weights (coalesced dwordx4, L1/L2-hot).
// ---------------------------------------------------------------------------
__global__ __launch_bounds__(256) void k1_proj(const float* __restrict__ X,
    const u16* __restrict__ wpack, u16* __restrict__ Q, u16* __restrict__ Kv)
{
  const int d = blockIdx.y;
  const int nBase = blockIdx.x * 64;
  const int wv = threadIdx.x >> 6;
  const int l  = threadIdx.x & 63;
  const int row16 = l & 15, g = l >> 4;
  int node_a = nBase + wv*16 + row16;
  int na = node_a < NN ? node_a : NN-1;          // clamp; stores are guarded
  const float* xrow = X + ((size_t)d*NN + na)*128;
  h8 a[4];
  #pragma unroll
  for (int ks = 0; ks < 4; ks++){
    float4 f0 = *(const float4*)(xrow + ks*32 + g*8);
    float4 f1 = *(const float4*)(xrow + ks*32 + g*8 + 4);
    a[ks] = pack8(f0, f1);
  }
  const uint4* wp4 = (const uint4*)wpack;
  #pragma unroll
  for (int ct = 0; ct < 8; ct++){
    f4 acc = {0.f, 0.f, 0.f, 0.f};
    #pragma unroll
    for (int ks = 0; ks < 4; ks++){
      U16 b; b.u = wp4[((d*8 + ct)*4 + ks)*64 + l];
      acc = __builtin_amdgcn_mfma_f32_16x16x32_f16(a[ks], b.h, acc, 0, 0, 0);
    }
    u16* dst = (ct < 4) ? Q : Kv;
    int cc = (ct & 3)*16 + row16;
    #pragma unroll
    for (int r = 0; r < 4; r++){
      int node = nBase + wv*16 + g*4 + r;        // D: col=lane&15, row=(lane>>4)*4+r
      if (node < NN) dst[(size_t)node*256 + d*64 + cc] = f2h_u(acc[r]);
    }
  }
}

// ---------------------------------------------------------------------------
// k2: per-wave 16 edges, fully wave-independent (no barriers).
//   stage1: gather q[n_i],k[n_j], f32 dot over d -> w tile -> swizzled LDS
//   stage2: mlp_t L1 (A from global t_ij) -> h (swizzled LDS)
//   stage3: mlp_t L2 -> accT (regs)
//   stage4: mlp_w L1 (A from w LDS) -> h
//   stage5: mlp_w L2 + fused bias/product epilogue, f32 stores (full 64B lines)
// LDS swizzle kills the stride-256B/128B 16-way bank conflict on ds_read_b128.
// ---------------------------------------------------------------------------
__global__ __launch_bounds__(256) void k2_edge(
    const u16* __restrict__ Q, const u16* __restrict__ Kv,
    const int* __restrict__ eidx, const float* __restrict__ T,
    const uint4* __restrict__ mw1p, const uint4* __restrict__ mw2p,
    const uint4* __restrict__ mt1p, const uint4* __restrict__ mt2p,
    const float* __restrict__ b1w, const float* __restrict__ b2w,
    const float* __restrict__ b1t, const float* __restrict__ b2t,
    float* __restrict__ out)
{
  __shared__ alignas(16) u16 w_lds[4][16*64];
  __shared__ alignas(16) u16 h_lds[4][16*128];
  const int wv = threadIdx.x >> 6;
  const int l  = threadIdx.x & 63;
  const int eBase = (blockIdx.x*4 + wv)*16;
  const int row16 = l & 15, g = l >> 4;

  // ---- stage 1: gather + edge dot ----
  {
    const int p = l & 3, er = l >> 2;
    const int eg = eBase + er;
    const int nj = eidx[eg];        // edge_index[0] = n_j (sender, uses ek)
    const int ni = eidx[EE + eg];   // edge_index[1] = n_i (receiver, uses eq)
    const u16* qb = Q  + (size_t)ni*256 + p*16;
    const u16* kb = Kv + (size_t)nj*256 + p*16;
    float acc16[16];
    #pragma unroll
    for (int j = 0; j < 16; j++) acc16[j] = 0.f;
    #pragma unroll
    for (int dd = 0; dd < 4; dd++){
      uint4 qa = *(const uint4*)(qb + dd*64);
      uint4 qc = *(const uint4*)(qb + dd*64 + 8);
      uint4 ka = *(const uint4*)(kb + dd*64);
      uint4 kc = *(const uint4*)(kb + dd*64 + 8);
      u32 qs[8] = {qa.x,qa.y,qa.z,qa.w,qc.x,qc.y,qc.z,qc.w};
      u32 ks_[8] = {ka.x,ka.y,ka.z,ka.w,kc.x,kc.y,kc.z,kc.w};
      #pragma unroll
      for (int j = 0; j < 8; j++){
        float2 qf = up2(qs[j]), kf = up2(ks_[j]);
        acc16[2*j]   += qf.x * kf.x;
        acc16[2*j+1] += qf.y * kf.y;
      }
    }
    uint4 wlo, whi;
    wlo.x = phh(acc16[0],acc16[1]);  wlo.y = phh(acc16[2],acc16[3]);
    wlo.z = phh(acc16[4],acc16[5]);  wlo.w = phh(acc16[6],acc16[7]);
    whi.x = phh(acc16[8],acc16[9]);  whi.y = phh(acc16[10],acc16[11]);
    whi.z = phh(acc16[12],acc16[13]); whi.w = phh(acc16[14],acc16[15]);
    int wbase = er*64 + ((p*16) ^ ((er & 3) << 4));   // 32B-granule XOR swizzle
    *(uint4*)&w_lds[wv][wbase]     = wlo;
    *(uint4*)&w_lds[wv][wbase + 8] = whi;
  }
  // no barrier needed: each wave reads only the LDS it wrote (in-order DS pipe)

  // ---- stage 2: mlp_t layer 1 ----
  {
    const float* trow = T + (size_t)(eBase + row16)*128;
    h8 at[4];
    #pragma unroll
    for (int ks = 0; ks < 4; ks++){
      float4 f0 = *(const float4*)(trow + ks*32 + g*8);
      float4 f1 = *(const float4*)(trow + ks*32 + g*8 + 4);
      at[ks] = pack8(f0, f1);
    }
    #pragma unroll
    for (int ct = 0; ct < 8; ct++){
      f4 acc = {0.f,0.f,0.f,0.f};
      #pragma unroll
      for (int ks = 0; ks < 4; ks++){
        U16 b; b.u = mt1p[(ct*4 + ks)*64 + l];
        acc = __builtin_amdgcn_mfma_f32_16x16x32_f16(at[ks], b.h, acc, 0, 0, 0);
      }
      float bb = b1t[ct*16 + row16];
      #pragma unroll
      for (int r = 0; r < 4; r++){
        int hr = g*4 + r;
        float v = fmaxf(acc[r] + bb, 0.f);
        h_lds[wv][hr*128 + ((ct*16 + row16) ^ ((hr & 7) << 3))] = f2h_u(v);
      }
    }
  }

  // ---- stage 3: mlp_t layer 2 -> accT ----
  f4 accT[8];
  {
    f4 z = {0.f,0.f,0.f,0.f};
    #pragma unroll
    for (int ct = 0; ct < 8; ct++) accT[ct] = z;
    #pragma unroll
    for (int ks = 0; ks < 4; ks++){
      U16 ah; ah.u = *(const uint4*)&h_lds[wv][row16*128 + ((ks*32 + g*8) ^ ((row16 & 7) << 3))];
      #pragma unroll
      for (int ct = 0; ct < 8; ct++){
        U16 b; b.u = mt2p[(ct*4 + ks)*64 + l];
        accT[ct] = __builtin_amdgcn_mfma_f32_16x16x32_f16(ah.h, b.h, accT[ct], 0, 0, 0);
      }
    }
  }

  // ---- stage 4: mlp_w layer 1 (A from w_lds) ----
  {
    h8 aw[2];
    #pragma unroll
    for (int ks = 0; ks < 2; ks++){
      U16 t; t.u = *(const uint4*)&w_lds[wv][row16*64 + ((ks*32 + g*8) ^ ((row16 & 3) << 4))];
      aw[ks] = t.h;
    }
    #pragma unroll
    for (int ct = 0; ct < 8; ct++){
      f4 acc = {0.f,0.f,0.f,0.f};
      U16 b0; b0.u = mw1p[(ct*2 + 0)*64 + l];
      acc = __builtin_amdgcn_mfma_f32_16x16x32_f16(aw[0], b0.h, acc, 0, 0, 0);
      U16 b1; b1.u = mw1p[(ct*2 + 1)*64 + l];
      acc = __builtin_amdgcn_mfma_f32_16x16x32_f16(aw[1], b1.h, acc, 0, 0, 0);
      float bb = b1w[ct*16 + row16];
      #pragma unroll
      for (int r = 0; r < 4; r++){
        int hr = g*4 + r;
        float v = fmaxf(acc[r] + bb, 0.f);
        h_lds[wv][hr*128 + ((ct*16 + row16) ^ ((hr & 7) << 3))] = f2h_u(v);
      }
    }
  }

  // ---- stage 5: mlp_w layer 2 + fused epilogue ----
  {
    h8 ah[4];
    #pragma unroll
    for (int ks = 0; ks < 4; ks++){
      U16 t; t.u = *(const uint4*)&h_lds[wv][row16*128 + ((ks*32 + g*8) ^ ((row16 & 7) << 3))];
      ah[ks] = t.h;
    }
    #pragma unroll
    for (int ct = 0; ct < 8; ct++){
      f4 acc = {0.f,0.f,0.f,0.f};
      #pragma unroll
      for (int ks = 0; ks < 4; ks++){
        U16 b; b.u = mw2p[(ct*4 + ks)*64 + l];
        acc = __builtin_amdgcn_mfma_f32_16x16x32_f16(ah[ks], b.h, acc, 0, 0, 0);
      }
      float bw = b2w[ct*16 + row16];
      float bt = b2t[ct*16 + row16];
      #pragma unroll
      for (int r = 0; r < 4; r++){
        float o = (acc[r] + bw) * (accT[ct][r] + bt);
        out[(size_t)(eBase + g*4 + r)*128 + ct*16 + row16] = o;
      }
    }
  }
}

extern "C" void kernel_launch(void* const* d_in, const int* in_sizes, int n_in,
                              void* d_out, int out_size, void* d_ws, size_t ws_size,
                              hipStream_t stream) {
  const float* X   = (const float*)d_in[0];
  const float* T   = (const float*)d_in[1];
  const int*   EI  = (const int*)  d_in[2];
  const float* Wq  = (const float*)d_in[3];
  const float* Wk  = (const float*)d_in[4];
  const float* w1w = (const float*)d_in[5];
  const float* b1w = (const float*)d_in[6];
  const float* w2w = (const float*)d_in[7];
  const float* b2w = (const float*)d_in[8];
  const float* w1t = (const float*)d_in[9];
  const float* b1t = (const float*)d_in[10];
  const float* w2t = (const float*)d_in[11];
  const float* b2t = (const float*)d_in[12];
  float* out = (float*)d_out;

  u16* ws   = (u16*)d_ws;
  u16* pack = ws;                       // 122880 u16 = 240 KB of packed weights
  u16* Q    = ws + 122880;              // [N][256] f16
  u16* Kv   = Q + (size_t)NN*256;       // [N][256] f16   (total ws use ~19.8 MB)

  k0_pack<<<64, 256, 0, stream>>>(Wq, Wk, w1w, w2w, w1t, w2t, pack);
  k1_proj<<<dim3((NN + 63)/64, 4), 256, 0, stream>>>(X, pack, Q, Kv);
  k2_edge<<<EE/64, 256, 0, stream>>>(Q, Kv, EI, T,
      (const uint4*)(ws + 65536), (const uint4*)(ws + 73728),
      (const uint4*)(ws + 90112), (const uint4*)(ws + 106496),
      b1w, b2w, b1t, b2t, out);
}